// Round 2
// baseline (340.271 us; speedup 1.0000x reference)
//
#include <hip/hip_runtime.h>

typedef float fx4 __attribute__((ext_vector_type(4)));   // native vector type for nontemporal builtins

__device__ __forceinline__ void nt_store4(float4* p, float4 v) {
    fx4 vv = {v.x, v.y, v.z, v.w};
    __builtin_nontemporal_store(vv, (fx4*)p);
}

// One thread per pose.
// - 3x float2 loads for xi (24 B, dense across the wave)
// - 4x float4 loads for the pose (independent -> deep MLP, no cross-lane ops)
// - R = I + A*W + B*W^2 with A = sin(t)/t, B = (1-cos(t))/t^2 as polynomials in t^2
//   (branchless; series limit == reference's small-angle branch; exact-libm
//   fallback for t >= 1.5 which never triggers for this data distribution)
// - 4x nontemporal float4 stores (output is write-once; keep inputs in L3)
__global__ __launch_bounds__(256) void se3_compose_kernel(
    const float* __restrict__ xi,
    const float4* __restrict__ poses4,   // flat float4 view, length 4*n
    float4* __restrict__ out4,           // flat float4 view, length 4*n
    int n)
{
    int p = blockIdx.x * blockDim.x + threadIdx.x;
    if (p >= n) return;

    // ---- xi[p, 0:6] ----
    const float2* x2 = (const float2*)(xi + 6ll * p);
    float2 a  = x2[0];   // t0 t1
    float2 b  = x2[1];   // t2 w0
    float2 cc = x2[2];   // w1 w2
    float t0 = a.x, t1 = a.y, t2 = b.x;
    float w0 = b.y, w1 = cc.x, w2 = cc.y;

    // ---- pose rows: 4 independent float4 loads ----
    const float4* P = poses4 + 4ll * p;
    float4 P0 = P[0];
    float4 P1 = P[1];
    float4 P2 = P[2];
    float4 P3 = P[3];

    // ---- A = sin(t)/t, B = (1-cos(t))/t^2 via series in x = t^2 ----
    float x = w0 * w0 + w1 * w1 + w2 * w2;   // theta^2
    float A, B;
    if (__builtin_expect(x < 2.25f, 1)) {
        // |err| < ~1.5e-6 for theta < 1.5
        A = 1.0f + x * (-1.0f / 6.0f   + x * (1.0f / 120.0f  + x * (-1.0f / 5040.0f  + x * (1.0f / 362880.0f))));
        B = 0.5f + x * (-1.0f / 24.0f  + x * (1.0f / 720.0f  + x * (-1.0f / 40320.0f + x * (1.0f / 3628800.0f))));
    } else {
        // exact path (never taken for this input distribution; keeps the kernel
        // mathematically correct for arbitrary xi)
        float th = sqrtf(x);
        float s  = sinf(th);
        float c  = cosf(th);
        A = s / th;
        B = (1.0f - c) / x;
    }

    // ---- R = I + A*W + B*W^2, W = skew(w) ----
    float w00 = w0 * w0, w11 = w1 * w1, w22 = w2 * w2;
    float R00 = 1.0f - B * (w11 + w22);
    float R11 = 1.0f - B * (w00 + w22);
    float R22 = 1.0f - B * (w00 + w11);
    float Bw01 = B * (w0 * w1), Bw02 = B * (w0 * w2), Bw12 = B * (w1 * w2);
    float Aw0 = A * w0, Aw1 = A * w1, Aw2 = A * w2;
    float R01 = Bw01 - Aw2, R10 = Bw01 + Aw2;
    float R02 = Bw02 + Aw1, R20 = Bw02 - Aw1;
    float R12 = Bw12 - Aw0, R21 = Bw12 + Aw0;

    // ---- out = T * P ----
    float4 o0, o1, o2;
    o0.x = R00 * P0.x + R01 * P1.x + R02 * P2.x + t0 * P3.x;
    o0.y = R00 * P0.y + R01 * P1.y + R02 * P2.y + t0 * P3.y;
    o0.z = R00 * P0.z + R01 * P1.z + R02 * P2.z + t0 * P3.z;
    o0.w = R00 * P0.w + R01 * P1.w + R02 * P2.w + t0 * P3.w;

    o1.x = R10 * P0.x + R11 * P1.x + R12 * P2.x + t1 * P3.x;
    o1.y = R10 * P0.y + R11 * P1.y + R12 * P2.y + t1 * P3.y;
    o1.z = R10 * P0.z + R11 * P1.z + R12 * P2.z + t1 * P3.z;
    o1.w = R10 * P0.w + R11 * P1.w + R12 * P2.w + t1 * P3.w;

    o2.x = R20 * P0.x + R21 * P1.x + R22 * P2.x + t2 * P3.x;
    o2.y = R20 * P0.y + R21 * P1.y + R22 * P2.y + t2 * P3.y;
    o2.z = R20 * P0.z + R21 * P1.z + R22 * P2.z + t2 * P3.z;
    o2.w = R20 * P0.w + R21 * P1.w + R22 * P2.w + t2 * P3.w;

    float4* O = out4 + 4ll * p;
    nt_store4(O + 0, o0);
    nt_store4(O + 1, o1);
    nt_store4(O + 2, o2);
    nt_store4(O + 3, P3);   // bottom row of T is [0,0,0,1] -> row 3 of P
}

extern "C" void kernel_launch(void* const* d_in, const int* in_sizes, int n_in,
                              void* d_out, int out_size, void* d_ws, size_t ws_size,
                              hipStream_t stream) {
    const float*  xi     = (const float*)d_in[0];
    const float4* poses4 = (const float4*)d_in[1];
    float4*       out4   = (float4*)d_out;

    int n = in_sizes[0] / 6;   // N = 2,000,000

    const int block = 256;
    const int grid  = (n + block - 1) / block;
    se3_compose_kernel<<<grid, block, 0, stream>>>(xi, poses4, out4, n);
}

// Round 3
// 249.053 us; speedup vs baseline: 1.3663x; 1.3663x over previous
//
#include <hip/hip_runtime.h>

typedef float fx4 __attribute__((ext_vector_type(4)));   // native vec type for nontemporal builtin

__device__ __forceinline__ void nt_store4(float4* p, float4 v) {
    fx4 vv = {v.x, v.y, v.z, v.w};
    __builtin_nontemporal_store(vv, (fx4*)p);
}

// Quad permute via DPP (VALU, no LDS/DS, no lgkmcnt): out[lane] = in[quad[lane]]
template<int CTRL>
__device__ __forceinline__ float qperm(float v) {
    return __int_as_float(__builtin_amdgcn_update_dpp(
        0, __float_as_int(v), CTRL, 0xF, 0xF, true));
}
template<int CTRL>
__device__ __forceinline__ float4 qperm4(float4 v) {
    float4 r;
    r.x = qperm<CTRL>(v.x);
    r.y = qperm<CTRL>(v.y);
    r.z = qperm<CTRL>(v.z);
    r.w = qperm<CTRL>(v.w);
    return r;
}

// quad_perm ctrl: bits[1:0]=src for lane0, [3:2]=lane1, [5:4]=lane2, [7:6]=lane3
#define ROT1 0xC9   // [1,2,0,3]: lane r<3 reads lane (r+1)%3; lane3 reads itself
#define ROT2 0xD2   // [2,0,1,3]: lane r<3 reads lane (r+2)%3; lane3 reads itself
#define BC3  0xFF   // [3,3,3,3]: broadcast lane 3

// 4 lanes per pose: lane j -> pose p=j>>2, row r=j&3. All global access coalesced 16B/lane.
// Rodrigues in cyclic form: row r of R = [diag -> col r, off1 -> col (r+1)%3, off2 -> col (r+2)%3]
//   diag = 1 - B*(wa^2+wb^2), off1 = B*wr*wa - A*wb, off2 = B*wr*wb + A*wa
// with wr=w[r], wa=w[(r+1)%3], wb=w[(r+2)%3], A=sin(t)/t, B=(1-cos(t))/t^2 (series in t^2).
// Cross-lane traffic: 3 float4 quad-perms (pose rows) + 2 scalar quad-perms (w) — all DPP.
__global__ __launch_bounds__(256) void se3_compose_kernel(
    const float* __restrict__ xi,
    const float4* __restrict__ poses4,   // flat float4 view, length 4*n
    float4* __restrict__ out4,           // flat float4 view, length 4*n
    int n4)                              // = 4*n (always a multiple of 4 -> whole quads)
{
    int i = blockIdx.x * blockDim.x + threadIdx.x;
    if (i >= n4) return;

    int p = i >> 2;   // pose index
    int r = i & 3;    // my row

    // ---- xi[p, 0:6] (quad-redundant; 3 wave-instructions, L1 broadcast) ----
    const float2* x2 = (const float2*)(xi + 6ll * p);
    float2 a  = x2[0];   // t0 t1
    float2 b  = x2[1];   // t2 w0
    float2 cc = x2[2];   // w1 w2
    float t0 = a.x, t1 = a.y, t2 = b.x;
    float w0 = b.y, w1 = cc.x, w2 = cc.y;

    // ---- my pose row: perfectly coalesced float4 ----
    float4 pr = poses4[i];

    // ---- A = sin(t)/t, B = (1-cos(t))/t^2, series in x = t^2 ----
    float x = w0 * w0 + w1 * w1 + w2 * w2;
    float A, B;
    if (__builtin_expect(x < 2.25f, 1)) {
        // |err| < ~1.5e-6 for theta < 1.5; series limit == reference small-angle branch
        A = 1.0f + x * (-1.0f / 6.0f  + x * (1.0f / 120.0f + x * (-1.0f / 5040.0f  + x * (1.0f / 362880.0f))));
        B = 0.5f + x * (-1.0f / 24.0f + x * (1.0f / 720.0f + x * (-1.0f / 40320.0f + x * (1.0f / 3628800.0f))));
    } else {
        // exact fallback (never taken for this distribution; keeps kernel general)
        float th = sqrtf(x);
        A = sinf(th) / th;
        B = (1.0f - cosf(th)) / x;
    }

    // ---- per-row values ----
    float wr = (r == 0) ? w0 : (r == 1) ? w1 : w2;                     // lane3: don't care
    float tr = (r == 0) ? t0 : (r == 1) ? t1 : (r == 2) ? t2 : 0.0f;

    float wa = qperm<ROT1>(wr);   // w[(r+1)%3]
    float wb = qperm<ROT2>(wr);   // w[(r+2)%3]

    float4 Pa = qperm4<ROT1>(pr); // pose row (r+1)%3
    float4 Pb = qperm4<ROT2>(pr); // pose row (r+2)%3
    float4 P3 = qperm4<BC3>(pr);  // pose row 3

    float diag = 1.0f - B * (wa * wa + wb * wb);
    float off1 = B * wr * wa - A * wb;
    float off2 = B * wr * wb + A * wa;
    if (r == 3) { diag = 1.0f; off1 = 0.0f; off2 = 0.0f; }  // T row 3 = [0,0,0,1] -> out = P3(own)

    float4 o;
    o.x = diag * pr.x + off1 * Pa.x + off2 * Pb.x + tr * P3.x;
    o.y = diag * pr.y + off1 * Pa.y + off2 * Pb.y + tr * P3.y;
    o.z = diag * pr.z + off1 * Pa.z + off2 * Pb.z + tr * P3.z;
    o.w = diag * pr.w + off1 * Pa.w + off2 * Pb.w + tr * P3.w;

    nt_store4(&out4[i], o);   // coalesced: wave writes 1KB contiguous -> full lines, nt safe
}

extern "C" void kernel_launch(void* const* d_in, const int* in_sizes, int n_in,
                              void* d_out, int out_size, void* d_ws, size_t ws_size,
                              hipStream_t stream) {
    const float*  xi     = (const float*)d_in[0];
    const float4* poses4 = (const float4*)d_in[1];
    float4*       out4   = (float4*)d_out;

    int n  = in_sizes[0] / 6;  // N = 2,000,000
    int n4 = 4 * n;

    const int block = 256;
    const int grid  = (n4 + block - 1) / block;
    se3_compose_kernel<<<grid, block, 0, stream>>>(xi, poses4, out4, n4);
}